// Round 3
// baseline (45.742 us; speedup 1.0000x reference)
//
#include <hip/hip_runtime.h>
#include <cmath>

// Problem constants (fixed by setup_inputs)
constexpr int B = 16, C = 3, H = 544, W = 960;
constexpr int OH = 136, OW = 240;
constexpr int TOH = 8, TOW = 30;     // output tile per block
constexpr int NTH = 17, NTW = 8;
constexpr int MH = 32, MW = 120;     // mag tile

constexpr int RAWW = 128;            // staged cols per row (mw0-4 .. mw0+123)
constexpr int CHROWS = 8;            // rows per chunk
constexpr int NCHUNK = 5;            // 40 gray rows (38 needed + 2 pad)
constexpr int CHW = CHROWS * RAWW;   // 1024 words per channel-chunk
constexpr int CHUNK_WORDS = 3 * CHW; // 3072 words = 12 KB
constexpr int TS = 124;              // tmp row stride (words)
constexpr int TROWS = 40;

typedef float __attribute__((address_space(1))) gfloat;
typedef float __attribute__((address_space(3))) lfloat;

__global__ __launch_bounds__(256)
void edge_kernel(const float* __restrict__ in, float* __restrict__ out,
                 float gn0, float gn1, float gn2)
{
    // raw RGB ring (2 x 12KB) + 8-word pad for benign tail overread
    __shared__ float raw[2 * CHUNK_WORDS + 8];   // 24608 B
    __shared__ float tmp[TROWS * TS];            // 19840 B  (h-blurred gray)

    const int tid  = threadIdx.x;
    const int lane = tid & 63;
    const int wv   = tid >> 6;

    const int blk = blockIdx.x;
    const int tw = blk % NTW;
    const int th = (blk / NTW) % NTH;
    const int b  = blk / (NTW * NTH);
    const int mh0 = th * MH;
    const int mw0 = tw * MW;
    const float* inb = in + (size_t)b * C * H * W;

    // lane-constant staging column (clamped for safety; edge cols fixed in convert)
    const int cg = lane & 31;
    int gcb = mw0 - 4 + 4 * cg;
    gcb = gcb < 0 ? 0 : (gcb > W - 4 ? W - 4 : gcb);
    const int rowadd = lane >> 5;

    // ---- DMA stage: one inst = 2 rows x 128 cols of one channel (1KB) ----
    auto stage = [&](int g, int bi) {
        const int r0tile = CHROWS * g;
        #pragma unroll
        for (int k = 0; k < 3; ++k) {
            const int item = 3 * wv + k;      // 0..11
            const int ch = item >> 2;
            const int pr = item & 3;
            const int lr = pr * 2 + rowadd;   // local chunk row (per-lane)
            int gr = mh0 - 3 + r0tile + lr;   // global row, reflect
            gr = gr < 0 ? -gr : (gr >= H ? 2 * H - 2 - gr : gr);
            const float* gp = inb + (size_t)ch * H * W + gr * W + gcb;
            lfloat* lp = (lfloat*)&raw[bi * CHUNK_WORDS + ch * CHW + pr * 2 * RAWW + lane * 4];
            __builtin_amdgcn_global_load_lds((const gfloat*)gp, lp, 16, 0, 0);
        }
    };

    // ---- convert: raw chunk -> gray -> horizontal 5-tap blur -> tmp ----
    auto convert = [&](int g, int bi) {
        if (tid < 248) {                       // 8 rows x 31 col-groups
            const int r = tid / 31;
            const int c = tid - r * 31;
            const int base = bi * CHUNK_WORDS + r * RAWW;
            float g8[8];                       // gray idx 4c+1 .. 4c+8
            const bool edge = (tw == 0 && c == 0) || (tw == 7 && c >= 29);
            if (!edge) {
                #pragma unroll
                for (int ch = 0; ch < 3; ++ch) {
                    const float wc = (ch == 0) ? 0.2989f : (ch == 1 ? 0.587f : 0.114f);
                    const float* p = &raw[base + ch * CHW + 4 * c];
                    const float4 a  = *reinterpret_cast<const float4*>(p);
                    const float4 bq = *reinterpret_cast<const float4*>(p + 4);
                    const float  s  = p[8];
                    const float arr[8] = {a.y, a.z, a.w, bq.x, bq.y, bq.z, bq.w, s};
                    #pragma unroll
                    for (int m = 0; m < 8; ++m)
                        g8[m] = (ch == 0) ? wc * arr[m] : fmaf(wc, arr[m], g8[m]);
                }
            } else {
                // column-boundary: scalar reads with reflect remap into staged tile
                #pragma unroll
                for (int m = 0; m < 8; ++m) {
                    int gc = mw0 - 4 + (4 * c + 1 + m);      // global col
                    gc = gc < 0 ? -gc : (gc >= W ? 2 * W - 2 - gc : gc);
                    const int gi = gc - (mw0 - 4);           // staged idx (0..127)
                    g8[m] = 0.2989f * raw[base + gi]
                          + 0.587f  * raw[base + CHW + gi]
                          + 0.114f  * raw[base + 2 * CHW + gi];
                }
            }
            float4 t;
            t.x = gn0 * g8[0] + gn1 * g8[1] + gn2 * g8[2] + gn1 * g8[3] + gn0 * g8[4];
            t.y = gn0 * g8[1] + gn1 * g8[2] + gn2 * g8[3] + gn1 * g8[4] + gn0 * g8[5];
            t.z = gn0 * g8[2] + gn1 * g8[3] + gn2 * g8[4] + gn1 * g8[5] + gn0 * g8[6];
            t.w = gn0 * g8[3] + gn1 * g8[4] + gn2 * g8[5] + gn1 * g8[6] + gn0 * g8[7];
            *reinterpret_cast<float4*>(&tmp[(CHROWS * g + r) * TS + 4 * c]) = t;
        }
    };

    // ---- pipelined staging loop: ring-2, counted vmcnt (never drains mid-loop) ----
    stage(0, 0);
    stage(1, 1);
    #pragma unroll
    for (int g = 0; g < NCHUNK; ++g) {
        if (g < NCHUNK - 1) asm volatile("s_waitcnt vmcnt(3)" ::: "memory");
        else                asm volatile("s_waitcnt vmcnt(0)" ::: "memory");
        __builtin_amdgcn_s_barrier();
        asm volatile("" ::: "memory");
        convert(g, g & 1);
        asm volatile("s_waitcnt lgkmcnt(0)" ::: "memory");
        __builtin_amdgcn_s_barrier();
        asm volatile("" ::: "memory");
        if (g + 2 < NCHUNK) stage(g + 2, g & 1);
    }

    // ---- stage 2: vertical blur (registers) + sobel + pool + sigmoid ----
    if (tid < TOH * TOW) {
        const int orow = tid / TOW;
        const int ocol = tid - orow * TOW;
        const int sr0 = orow * 4;      // tmp row base (reads tmp rows sr0..sr0+9)
        const int tc0 = ocol * 4;      // tmp col base (reads cols tc0..tc0+5)

        float sm[6][6];
        #pragma unroll
        for (int i = 0; i < 6; ++i)
            #pragma unroll
            for (int j = 0; j < 6; ++j) sm[i][j] = 0.f;

        const float gk[5] = {gn0, gn1, gn2, gn1, gn0};
        #pragma unroll
        for (int tr = 0; tr < 10; ++tr) {
            const float* p = &tmp[(sr0 + tr) * TS + tc0];
            const float4 u = *reinterpret_cast<const float4*>(p);
            const float4 v = *reinterpret_cast<const float4*>(p + 4);
            const float t6[6] = {u.x, u.y, u.z, u.w, v.x, v.y};
            #pragma unroll
            for (int i = 0; i < 6; ++i) {
                const int k = tr - i;
                if (k >= 0 && k < 5) {
                    #pragma unroll
                    for (int j = 0; j < 6; ++j)
                        sm[i][j] = fmaf(gk[k], t6[j], sm[i][j]);
                }
            }
        }

        // sobel zero-padding: zero sm outside the image
        #pragma unroll
        for (int i = 0; i < 6; ++i) {
            const int hh = mh0 - 1 + sr0 + i;
            const float rm = (hh >= 0 && hh < H) ? 1.f : 0.f;
            #pragma unroll
            for (int j = 0; j < 6; ++j) {
                const int ww = mw0 - 1 + tc0 + j;
                const float cm = (ww >= 0 && ww < W) ? 1.f : 0.f;
                sm[i][j] *= rm * cm;
            }
        }

        float acc = 0.f;
        #pragma unroll
        for (int i = 0; i < 4; ++i) {
            #pragma unroll
            for (int j = 0; j < 4; ++j) {
                const float a00 = sm[i][j],     a01 = sm[i][j + 1],     a02 = sm[i][j + 2];
                const float a10 = sm[i + 1][j],                         a12 = sm[i + 1][j + 2];
                const float a20 = sm[i + 2][j], a21 = sm[i + 2][j + 1], a22 = sm[i + 2][j + 2];
                const float gx = (a02 - a00) + 2.f * (a12 - a10) + (a22 - a20);
                const float gy = (a20 + 2.f * a21 + a22) - (a00 + 2.f * a01 + a02);
                acc += sqrtf(gx * gx + gy * gy + 1e-6f);
            }
        }
        const float down = acc * (1.f / 16.f);
        const float x = 5.0f * (down - 0.2f);
        const float sg = 1.f / (1.f + expf(-x));
        const size_t o = ((size_t)b * OH + (th * TOH + orow)) * OW + (tw * TOW + ocol);
        out[o] = sg * sg;
    }
}

extern "C" void kernel_launch(void* const* d_in, const int* in_sizes, int n_in,
                              void* d_out, int out_size, void* d_ws, size_t ws_size,
                              hipStream_t stream) {
    const float* in = (const float*)d_in[0];
    float* out = (float*)d_out;

    // Gaussian 1D coefficients (separable: outer(g,g)/(sum g)^2), exact in double.
    const double g0 = std::exp(-4.0 / 4.5);  // x=2
    const double g1 = std::exp(-1.0 / 4.5);  // x=1
    const double g2 = 1.0;                   // x=0
    const double S = 2.0 * (g0 + g1) + g2;
    const float gn0 = (float)(g0 / S);
    const float gn1 = (float)(g1 / S);
    const float gn2 = (float)(g2 / S);

    dim3 grid(B * NTH * NTW);  // 2176 blocks
    dim3 block(256);
    hipLaunchKernelGGL(edge_kernel, grid, block, 0, stream,
                       in, out, gn0, gn1, gn2);
}

// Round 4
// 43.213 us; speedup vs baseline: 1.0585x; 1.0585x over previous
//
#include <hip/hip_runtime.h>
#include <cmath>

// Problem constants (fixed by setup_inputs)
constexpr int B = 16, C = 3, H = 544, W = 960;
constexpr int OH = 136, OW = 240;
constexpr int TOH = 8, TOW = 30;     // output tile per block
constexpr int NTH = 17, NTW = 8;
constexpr int MH = 32, MW = 120;     // mag tile

// tmp: horizontally-blurred gray. tmp[r][j] <-> global row mh0-3+r, col mw0-1+j.
constexpr int TR = 38;               // rows
constexpr int TS = 124;              // row stride (floats); cols 0..121 valid
constexpr int TC4 = 31;              // float4 col-groups per row
constexpr int NTASK = TR * TC4;     // 1178

__global__ __launch_bounds__(256, 6)
void edge_kernel(const float* __restrict__ in, float* __restrict__ out,
                 float gn0, float gn1, float gn2)
{
    __shared__ float tmp[TR * TS];   // 18848 B -> 8 blocks/CU

    const int tid = threadIdx.x;
    const int blk = blockIdx.x;
    const int tw = blk % NTW;
    const int th = (blk / NTW) % NTH;
    const int b  = blk / (NTW * NTH);
    const int mh0 = th * MH;
    const int mw0 = tw * MW;
    const float* inb = in + (size_t)b * C * H * W;

    // ---- stage A: RGB -> gray -> horizontal 5-tap blur, all in registers ----
    // task (r,c): compute tmp[r][4c..4c+3] from gray global cols gcb+1 .. gcb+8,
    // gcb = mw0-4+4c (16B-aligned). Fast path: 2 float4 + 1 scalar per channel.
    for (int idx = tid; idx < NTASK; idx += 256) {
        const int r = idx / TC4;
        const int c = idx - r * TC4;
        int gr = mh0 - 3 + r;                       // row reflect
        gr = gr < 0 ? -gr : (gr >= H ? 2 * H - 2 - gr : gr);
        const int gcb = mw0 - 4 + 4 * c;
        float g8[8];                                // gray at global cols gcb+1..gcb+8
        if (gcb >= 0 && gcb + 8 < W) {
            #pragma unroll
            for (int ch = 0; ch < 3; ++ch) {
                const float wc = (ch == 0) ? 0.2989f : (ch == 1 ? 0.587f : 0.114f);
                const float* p = inb + (size_t)ch * H * W + (size_t)gr * W + gcb;
                const float4 a  = *reinterpret_cast<const float4*>(p);
                const float4 b4 = *reinterpret_cast<const float4*>(p + 4);
                const float  s  = p[8];
                const float arr[8] = {a.y, a.z, a.w, b4.x, b4.y, b4.z, b4.w, s};
                #pragma unroll
                for (int m = 0; m < 8; ++m)
                    g8[m] = (ch == 0) ? wc * arr[m] : fmaf(wc, arr[m], g8[m]);
            }
        } else {
            // column-boundary blocks only: scalar loads with col reflect
            #pragma unroll
            for (int m = 0; m < 8; ++m) {
                int gc = gcb + 1 + m;
                gc = gc < 0 ? -gc : (gc >= W ? 2 * W - 2 - gc : gc);
                const float* p = inb + (size_t)gr * W + gc;
                g8[m] = 0.2989f * p[0] + 0.587f * p[H * W] + 0.114f * p[2 * H * W];
            }
        }
        float4 t;
        t.x = gn0 * g8[0] + gn1 * g8[1] + gn2 * g8[2] + gn1 * g8[3] + gn0 * g8[4];
        t.y = gn0 * g8[1] + gn1 * g8[2] + gn2 * g8[3] + gn1 * g8[4] + gn0 * g8[5];
        t.z = gn0 * g8[2] + gn1 * g8[3] + gn2 * g8[4] + gn1 * g8[5] + gn0 * g8[6];
        t.w = gn0 * g8[3] + gn1 * g8[4] + gn2 * g8[5] + gn1 * g8[6] + gn0 * g8[7];
        *reinterpret_cast<float4*>(&tmp[r * TS + 4 * c]) = t;
    }
    __syncthreads();

    // ---- stage B: vertical blur (registers) + sobel + pool + sigmoid ----
    if (tid < TOH * TOW) {
        const int orow = tid / TOW;
        const int ocol = tid - orow * TOW;
        const int sr0 = orow * 4;      // reads tmp rows sr0..sr0+9
        const int tc0 = ocol * 4;      // reads tmp cols tc0..tc0+5

        float sm[6][6];
        #pragma unroll
        for (int i = 0; i < 6; ++i)
            #pragma unroll
            for (int j = 0; j < 6; ++j) sm[i][j] = 0.f;

        const float gk[5] = {gn0, gn1, gn2, gn1, gn0};
        #pragma unroll
        for (int tr = 0; tr < 10; ++tr) {
            const float* p = &tmp[(sr0 + tr) * TS + tc0];
            const float4 u = *reinterpret_cast<const float4*>(p);
            const float4 v = *reinterpret_cast<const float4*>(p + 4);
            const float t6[6] = {u.x, u.y, u.z, u.w, v.x, v.y};
            #pragma unroll
            for (int i = 0; i < 6; ++i) {
                const int k = tr - i;
                if (k >= 0 && k < 5) {
                    #pragma unroll
                    for (int j = 0; j < 6; ++j)
                        sm[i][j] = fmaf(gk[k], t6[j], sm[i][j]);
                }
            }
        }

        // sobel zero-padding: zero sm outside the image
        #pragma unroll
        for (int i = 0; i < 6; ++i) {
            const int hh = mh0 - 1 + sr0 + i;
            const float rm = (hh >= 0 && hh < H) ? 1.f : 0.f;
            #pragma unroll
            for (int j = 0; j < 6; ++j) {
                const int ww = mw0 - 1 + tc0 + j;
                const float cm = (ww >= 0 && ww < W) ? 1.f : 0.f;
                sm[i][j] *= rm * cm;
            }
        }

        float acc = 0.f;
        #pragma unroll
        for (int i = 0; i < 4; ++i) {
            #pragma unroll
            for (int j = 0; j < 4; ++j) {
                const float a00 = sm[i][j],     a01 = sm[i][j + 1],     a02 = sm[i][j + 2];
                const float a10 = sm[i + 1][j],                         a12 = sm[i + 1][j + 2];
                const float a20 = sm[i + 2][j], a21 = sm[i + 2][j + 1], a22 = sm[i + 2][j + 2];
                const float gx = (a02 - a00) + 2.f * (a12 - a10) + (a22 - a20);
                const float gy = (a20 + 2.f * a21 + a22) - (a00 + 2.f * a01 + a02);
                acc += sqrtf(gx * gx + gy * gy + 1e-6f);
            }
        }
        const float down = acc * (1.f / 16.f);
        const float x = 5.0f * (down - 0.2f);
        const float sg = 1.f / (1.f + expf(-x));
        const size_t o = ((size_t)b * OH + (th * TOH + orow)) * OW + (tw * TOW + ocol);
        out[o] = sg * sg;
    }
}

extern "C" void kernel_launch(void* const* d_in, const int* in_sizes, int n_in,
                              void* d_out, int out_size, void* d_ws, size_t ws_size,
                              hipStream_t stream) {
    const float* in = (const float*)d_in[0];
    float* out = (float*)d_out;

    // Gaussian 1D coefficients (separable: outer(g,g)/(sum g)^2), exact in double.
    const double g0 = std::exp(-4.0 / 4.5);  // x=2
    const double g1 = std::exp(-1.0 / 4.5);  // x=1
    const double g2 = 1.0;                   // x=0
    const double S = 2.0 * (g0 + g1) + g2;
    const float gn0 = (float)(g0 / S);
    const float gn1 = (float)(g1 / S);
    const float gn2 = (float)(g2 / S);

    dim3 grid(B * NTH * NTW);  // 2176 blocks
    dim3 block(256);
    hipLaunchKernelGGL(edge_kernel, grid, block, 0, stream,
                       in, out, gn0, gn1, gn2);
}